// Round 3
// baseline (329.881 us; speedup 1.0000x reference)
//
#include <hip/hip_runtime.h>
#include <hip/hip_bf16.h>

// Problem: B=8, N=4096, E=65536, D=256
// h = x@W^T + b; agg = segment_sum(h[src]*m_s*m_t by tgt); h += agg/64;
// out = relu(LN(h)*gamma+beta) * mask
#define NN 4096
#define DIM 256
#define NE 65536
#define TOT_NODES 32768
#define TOT_EDGES 524288

// ---- runtime-dtype accessors (flags decided on device by detect_kernel) ----------
__device__ __forceinline__ float ldf(const void* p, int isbf, size_t i) {
    return isbf ? __bfloat162float(((const __hip_bfloat16*)p)[i]) : ((const float*)p)[i];
}
__device__ __forceinline__ void stf(void* p, int isbf, size_t i, float v) {
    if (isbf) ((__hip_bfloat16*)p)[i] = __float2bfloat16(v);
    else      ((float*)p)[i] = v;
}
__device__ __forceinline__ int ldi(const void* p, int is64, size_t i) {
    return is64 ? (int)((const long long*)p)[i] : ((const int*)p)[i];
}

// flags[0]=edge_index is int64, flags[1]=node_mask is int64, flags[2]=floats are bf16
__global__ void detect_kernel(const void* ei, const void* nm, const void* x, int* flags) {
    const int t = threadIdx.x;
    const long long ev = ((const long long*)ei)[t];
    const unsigned long long okE = __ballot(ev >= 0 && ev < NN);
    const long long mv = ((const long long*)nm)[t];
    const unsigned long long okM = __ballot(mv == 0 || mv == 1);
    // low 16 bits of each 32b word: for bf16 storage this is the even-index bf16
    // element (exp field biased near 127 for N(0,1)); for fp32 it's uniform mantissa bits.
    const unsigned int w = ((const unsigned int*)x)[t];
    const int e = (w >> 7) & 0xFF;
    const unsigned long long okF = __ballot(e >= 100 && e <= 140);
    if (t == 0) {
        flags[0] = (okE == ~0ULL) ? 1 : 0;
        flags[1] = (okM == ~0ULL) ? 1 : 0;
        flags[2] = (__popcll(okF) >= 40) ? 1 : 0;
    }
}

__global__ __launch_bounds__(256)
void init_kernel(int* __restrict__ counts) {
    counts[blockIdx.x * 256 + threadIdx.x] = 0;
}

// ---------------- GEMM (VALU, diagnosis round): h[m][n] = sum_k x[m][k]W[n][k]+b[n]
// block = 256 threads (thread t = output col n), 16 m-rows per block.
__global__ __launch_bounds__(256)
void gemm_kernel(const void* __restrict__ x, const void* __restrict__ w,
                 const void* __restrict__ bias, const int* __restrict__ flags,
                 float* __restrict__ h)
{
    __shared__ float xs[16 * 256];
    const int fbf = flags[2];
    const int t = threadIdx.x;
    const int m0 = blockIdx.x * 16;
    for (int i = t; i < 16 * 256; i += 256)
        xs[i] = ldf(x, fbf, (size_t)m0 * 256 + i);
    __syncthreads();
    float acc[16];
    const float bv = ldf(bias, fbf, t);
#pragma unroll
    for (int mi = 0; mi < 16; ++mi) acc[mi] = bv;
    if (fbf) {
        const __hip_bfloat16* wr = (const __hip_bfloat16*)w + (size_t)t * 256;
        for (int k = 0; k < 256; ++k) {
            const float wv = __bfloat162float(wr[k]);
#pragma unroll
            for (int mi = 0; mi < 16; ++mi) acc[mi] += xs[mi * 256 + k] * wv;
        }
    } else {
        const float* wr = (const float*)w + (size_t)t * 256;
        for (int k = 0; k < 256; ++k) {
            const float wv = wr[k];
#pragma unroll
            for (int mi = 0; mi < 16; ++mi) acc[mi] += xs[mi * 256 + k] * wv;
        }
    }
#pragma unroll
    for (int mi = 0; mi < 16; ++mi)
        h[(size_t)(m0 + mi) * 256 + t] = acc[mi];
}

// ---------------- CSR build: count -> scan -> fill ---------------------------------
__global__ __launch_bounds__(256)
void count_kernel(const void* __restrict__ ei, const void* __restrict__ nm,
                  const int* __restrict__ flags, int* __restrict__ counts)
{
    const int e64 = flags[0], m64 = flags[1];
    const int tid = blockIdx.x * 256 + threadIdx.x;
    const int b = tid >> 16;          // NE = 65536
    const int e = tid & (NE - 1);
    const size_t eb = (size_t)b * 2 * NE;
    const int src = ldi(ei, e64, eb + e);
    const int tgt = ldi(ei, e64, eb + NE + e);
    const size_t mb = (size_t)b * NN;
    if (ldi(nm, m64, mb + src) && ldi(nm, m64, mb + tgt))
        atomicAdd(&counts[b * NN + tgt], 1);
}

// single block, 256 threads x 128; writes exclusive offsets and inits cursor
__global__ __launch_bounds__(256)
void scan_kernel(int* __restrict__ counts, int* __restrict__ offsets)
{
    __shared__ int sums[256];
    const int t = threadIdx.x;
    const int base = t * 128;
    int s = 0;
    for (int i = 0; i < 128; ++i) s += counts[base + i];
    sums[t] = s;
    __syncthreads();
    for (int off = 1; off < 256; off <<= 1) {
        int v = (t >= off) ? sums[t - off] : 0;
        __syncthreads();
        sums[t] += v;
        __syncthreads();
    }
    int run = sums[t] - s;
    for (int i = 0; i < 128; ++i) {
        const int c = counts[base + i];
        offsets[base + i] = run;
        counts[base + i] = run;     // cursor init for fill_kernel
        run += c;
    }
    if (t == 255) offsets[TOT_NODES] = sums[255];
}

__global__ __launch_bounds__(256)
void fill_kernel(const void* __restrict__ ei, const void* __restrict__ nm,
                 const int* __restrict__ flags,
                 int* __restrict__ cursor, int* __restrict__ bucket)
{
    const int e64 = flags[0], m64 = flags[1];
    const int tid = blockIdx.x * 256 + threadIdx.x;
    const int b = tid >> 16;
    const int e = tid & (NE - 1);
    const size_t eb = (size_t)b * 2 * NE;
    const int src = ldi(ei, e64, eb + e);
    const int tgt = ldi(ei, e64, eb + NE + e);
    const size_t mb = (size_t)b * NN;
    if (ldi(nm, m64, mb + src) && ldi(nm, m64, mb + tgt)) {
        int pos = atomicAdd(&cursor[b * NN + tgt], 1);
        bucket[pos] = src;
    }
}

// ---------------- gather + residual + LayerNorm + ReLU + mask ----------------------
__global__ __launch_bounds__(256)
void node_kernel(const float* __restrict__ h, const int* __restrict__ offsets,
                 const int* __restrict__ bucket, const void* __restrict__ nm,
                 const int* __restrict__ flags,
                 const void* __restrict__ gamma, const void* __restrict__ beta,
                 void* __restrict__ out)
{
    const int bt = blockIdx.x;
    const int d = threadIdx.x;
    const size_t obase = (size_t)bt * DIM;
    const int m64 = flags[1], fbf = flags[2];
    if (!ldi(nm, m64, bt)) { stf(out, fbf, obase + d, 0.f); return; }
    const int b = bt >> 12;     // NN = 4096
    const float* hb = h + ((size_t)b << 12) * DIM;
    const float self = h[obase + d];
    const int s0 = offsets[bt], s1 = offsets[bt + 1];
    float a0 = 0.f, a1 = 0.f, a2 = 0.f, a3 = 0.f;
    int j = s0;
    for (; j + 4 <= s1; j += 4) {
        const int i0 = bucket[j], i1 = bucket[j + 1], i2 = bucket[j + 2], i3 = bucket[j + 3];
        a0 += hb[(size_t)i0 * DIM + d];
        a1 += hb[(size_t)i1 * DIM + d];
        a2 += hb[(size_t)i2 * DIM + d];
        a3 += hb[(size_t)i3 * DIM + d];
    }
    for (; j < s1; ++j) a0 += hb[(size_t)bucket[j] * DIM + d];
    const float acc = self + ((a0 + a1) + (a2 + a3)) * 0.015625f;   // /sqrt(4096)

    float v1 = acc, v2 = acc * acc;
#pragma unroll
    for (int off = 32; off > 0; off >>= 1) {
        v1 += __shfl_down(v1, off, 64);
        v2 += __shfl_down(v2, off, 64);
    }
    __shared__ float red[8];
    const int wv = d >> 6, ln = d & 63;
    if (ln == 0) { red[wv] = v1; red[4 + wv] = v2; }
    __syncthreads();
    const float S1 = red[0] + red[1] + red[2] + red[3];
    const float S2 = red[4] + red[5] + red[6] + red[7];
    const float mu = S1 * (1.f / 256.f);
    const float var = S2 * (1.f / 256.f) - mu * mu;
    const float inv = rsqrtf(var + 1e-5f);
    float y = (acc - mu) * inv * ldf(gamma, fbf, d) + ldf(beta, fbf, d);
    y = fmaxf(y, 0.f);
    stf(out, fbf, obase + d, y);
}

// host-side sentinel buffer for launch-failure diagnosis (static lifetime: safe
// for async H2D copy; value encodes the first failing stage as absmax ~ 1e4*stage)
static float g_sentinel[256];

extern "C" void kernel_launch(void* const* d_in, const int* in_sizes, int n_in,
                              void* d_out, int out_size, void* d_ws, size_t ws_size,
                              hipStream_t stream)
{
    (void)in_sizes; (void)n_in; (void)out_size;
    const void* x     = d_in[0];
    const void* W     = d_in[1];
    const void* bias  = d_in[2];
    const void* gamma = d_in[3];
    const void* beta  = d_in[4];
    const void* ei    = d_in[5];
    const void* nm    = d_in[6];

    char* ws = (char*)d_ws;
    int* flags   = (int*)ws;                 // @0        12 B
    int* counts  = (int*)(ws + 256);         // @256      131072 B (becomes cursor)
    int* offsets = (int*)(ws + 131328);      // @131328   131076 B
    int* bucket  = (int*)(ws + 262656);      // @262656   2097152 B
    float* h     = (float*)(ws + 2359808);   // @2359808  33554432 B (fp32 h)

    int fail = 0;
    hipGetLastError();  // clear any pre-existing error
#define CHK(stage) do { if (!fail && hipGetLastError() != hipSuccess) fail = (stage); } while (0)

    detect_kernel<<<1, 64, 0, stream>>>(ei, nm, x, flags);                       CHK(1);
    init_kernel<<<TOT_NODES / 256, 256, 0, stream>>>(counts);                    CHK(2);
    gemm_kernel<<<TOT_NODES / 16, 256, 0, stream>>>(x, W, bias, flags, h);       CHK(3);
    count_kernel<<<TOT_EDGES / 256, 256, 0, stream>>>(ei, nm, flags, counts);    CHK(4);
    scan_kernel<<<1, 256, 0, stream>>>(counts, offsets);                         CHK(5);
    fill_kernel<<<TOT_EDGES / 256, 256, 0, stream>>>(ei, nm, flags, counts, bucket); CHK(6);
    node_kernel<<<TOT_NODES, 256, 0, stream>>>(h, offsets, bucket, nm, flags,
                                               gamma, beta, d_out);              CHK(7);
#undef CHK

    if (fail) {   // deterministic per-environment -> graph-capture safe
        for (int i = 0; i < 256; ++i) g_sentinel[i] = 10000.f * (float)fail;
        hipMemcpyAsync(d_out, g_sentinel, sizeof(g_sentinel),
                       hipMemcpyHostToDevice, stream);
    }
}